// Round 3
// baseline (8337.466 us; speedup 1.0000x reference)
//
#include <hip/hip_runtime.h>

// 3D reaction-diffusion tumor solver, 160^3 f32, 30 explicit Euler steps.
// c_{t+1} = clip(c + (D*lap(c) + rho*c*(1-c) - 2*ther*c)*dt/steps, 0, 1)
//
// R3: single persistent kernel, 30 steps separated by a manual grid barrier
// (1024 blocks = exactly 4/CU, co-residency forced by __launch_bounds__(256,4)).
// Each thread owns 4 consecutive z-levels of one float4 x-group: center loads
// z-1..z+4 shared across outputs (18 f4 + 8 scalar loads / 4 outputs).
// therapy + scalar params hoisted into registers across all 30 steps.

#define NX 160
#define NY 160
#define NZ 160
#define NXQ 40                    // float4 groups per row
#define NPLANE (NX * NY)          // 25600 floats per z-plane
#define NZQ 40                    // z-quads per column
#define NWORK (NXQ * NY * NZQ)    // 256000 working threads (blocks 0..999)
#define NBLOCKS 1024              // 4 blocks/CU on 256 CUs -> all co-resident
#define NSTEPS 30

__device__ __forceinline__ float4 ld4(const float* p) {
    return *reinterpret_cast<const float4*>(p);
}

__device__ __forceinline__ void grid_barrier(unsigned int* cnt, unsigned int target) {
    __threadfence();              // release: flush this thread's stores device-wide
    __syncthreads();
    if (threadIdx.x == 0) {
        __hip_atomic_fetch_add(cnt, 1u, __ATOMIC_RELEASE, __HIP_MEMORY_SCOPE_AGENT);
        while (__hip_atomic_load(cnt, __ATOMIC_ACQUIRE, __HIP_MEMORY_SCOPE_AGENT) < target) {
            __builtin_amdgcn_s_sleep(1);
        }
    }
    __syncthreads();
    __threadfence();              // acquire: invalidate caches before reading peers' data
}

__global__ void init_counter(unsigned int* cnt) {
    *cnt = 0u;
}

__global__ __launch_bounds__(256, 4) void therapy_persistent(
    const float* __restrict__ c_init,
    const float* __restrict__ ther,
    float* __restrict__ bufA,         // ws ping buffer
    float* __restrict__ out,          // d_out, doubles as pong buffer
    unsigned int* __restrict__ counter,
    const float* __restrict__ Dp,
    const float* __restrict__ rhop,
    const float* __restrict__ dtp,
    const int* __restrict__ stepsp)
{
    const int tid = blockIdx.x * blockDim.x + threadIdx.x;
    const bool active = (tid < NWORK);   // blocks 1000..1023 only barrier

    int xq = 0, y = 0, zq = 0;
    if (active) {
        xq = tid % NXQ;
        y  = (tid / NXQ) % NY;
        zq = tid / (NXQ * NY);           // 0..39, owns z = 4*zq .. 4*zq+3
    }
    const int idx0 = ((zq * 4) * NY + y) * NX + xq * 4;

    // Always-valid clamped offsets; boundary values masked to zero below.
    const int offym = (y > 0)        ? -NX : 0;
    const int offyp = (y < NY - 1)   ?  NX : 0;
    const int offxl = (xq > 0)       ? -1  : 0;
    const int offxr = (xq < NXQ - 1) ?  4  : 3;
    const int offzm = (zq > 0)       ? -NPLANE     : 0;
    const int offzp = (zq < NZQ - 1) ?  4 * NPLANE : 3 * NPLANE;

    const float D       = *Dp;
    const float rho     = *rhop;
    const float delta_t = *dtp / (float)(*stepsp);
    const float4 zero4  = make_float4(0.f, 0.f, 0.f, 0.f);

    // therapy is time-invariant: hold in registers for all 30 steps
    float4 tm[4];
    if (active) {
        #pragma unroll
        for (int i = 0; i < 4; ++i) tm[i] = ld4(ther + idx0 + i * NPLANE);
    } else {
        #pragma unroll
        for (int i = 0; i < 4; ++i) tm[i] = zero4;
    }

    const float* src = c_init;
    #pragma unroll 2
    for (int s = 0; s < NSTEPS; ++s) {
        float* dst = (s & 1) ? out : bufA;   // step 29 (odd) lands in d_out
        if (active) {
            const float* sp = src + idx0;
            float4 cz[6];                    // z-1, z, z+1, z+2, z+3, z+4
            float4 ymv[4], ypv[4];
            float  xlv[4], xrv[4];
            #pragma unroll
            for (int i = 0; i < 4; ++i) {
                cz[i + 1] = ld4(sp + i * NPLANE);
                ymv[i]    = ld4(sp + i * NPLANE + offym);
                ypv[i]    = ld4(sp + i * NPLANE + offyp);
                xlv[i]    = sp[i * NPLANE + offxl];
                xrv[i]    = sp[i * NPLANE + offxr];
            }
            cz[0] = ld4(sp + offzm);
            cz[5] = ld4(sp + offzp);

            if (zq == 0)       cz[0] = zero4;
            if (zq == NZQ - 1) cz[5] = zero4;
            if (y == 0)      { ymv[0] = ymv[1] = ymv[2] = ymv[3] = zero4; }
            if (y == NY - 1) { ypv[0] = ypv[1] = ypv[2] = ypv[3] = zero4; }
            if (xq == 0)       { xlv[0] = xlv[1] = xlv[2] = xlv[3] = 0.f; }
            if (xq == NXQ - 1) { xrv[0] = xrv[1] = xrv[2] = xrv[3] = 0.f; }

            #pragma unroll
            for (int i = 0; i < 4; ++i) {
                const float4 cc = cz[i + 1];
                const float4 zm = cz[i];
                const float4 zp = cz[i + 2];
                float4 o;
                float lap, g;
                lap = xlv[i] + cc.y + ymv[i].x + ypv[i].x + zm.x + zp.x - 6.f * cc.x;
                g   = D * lap + rho * cc.x * (1.f - cc.x) - 2.f * tm[i].x * cc.x;
                o.x = fminf(fmaxf(cc.x + g * delta_t, 0.f), 1.f);
                lap = cc.x + cc.z + ymv[i].y + ypv[i].y + zm.y + zp.y - 6.f * cc.y;
                g   = D * lap + rho * cc.y * (1.f - cc.y) - 2.f * tm[i].y * cc.y;
                o.y = fminf(fmaxf(cc.y + g * delta_t, 0.f), 1.f);
                lap = cc.y + cc.w + ymv[i].z + ypv[i].z + zm.z + zp.z - 6.f * cc.z;
                g   = D * lap + rho * cc.z * (1.f - cc.z) - 2.f * tm[i].z * cc.z;
                o.z = fminf(fmaxf(cc.z + g * delta_t, 0.f), 1.f);
                lap = cc.z + xrv[i] + ymv[i].w + ypv[i].w + zm.w + zp.w - 6.f * cc.w;
                g   = D * lap + rho * cc.w * (1.f - cc.w) - 2.f * tm[i].w * cc.w;
                o.w = fminf(fmaxf(cc.w + g * delta_t, 0.f), 1.f);
                *reinterpret_cast<float4*>(dst + idx0 + i * NPLANE) = o;
            }
        }
        if (s != NSTEPS - 1) {
            grid_barrier(counter, (unsigned)(s + 1) * NBLOCKS);
        }
        src = dst;
    }
}

extern "C" void kernel_launch(void* const* d_in, const int* in_sizes, int n_in,
                              void* d_out, int out_size, void* d_ws, size_t ws_size,
                              hipStream_t stream) {
    const float* c_init = (const float*)d_in[0];
    const float* Dp     = (const float*)d_in[1];
    const float* rhop   = (const float*)d_in[2];
    const float* dtp    = (const float*)d_in[3];
    const float* ther   = (const float*)d_in[4];
    const int*   stepsp = (const int*)d_in[5];

    float* out = (float*)d_out;
    unsigned int* counter = (unsigned int*)d_ws;          // 1 cacheline
    float* bufA = (float*)((char*)d_ws + 1024);           // 16.4 MB ping buffer

    // ws is re-poisoned 0xAA before every call: zero the barrier counter first
    // (same stream -> ordered before the persistent kernel).
    init_counter<<<1, 1, 0, stream>>>(counter);

    therapy_persistent<<<dim3(NBLOCKS), dim3(256), 0, stream>>>(
        c_init, ther, bufA, out, counter, Dp, rhop, dtp, stepsp);
}

// Round 4
// 4011.151 us; speedup vs baseline: 2.0786x; 2.0786x over previous
//
#include <hip/hip_runtime.h>

// 3D reaction-diffusion tumor solver, 160^3 f32, 30 explicit Euler steps.
// c_{t+1} = clip(c + (D*lap(c) + rho*c*(1-c) - 2*ther*c)*dt/steps, 0, 1)
//
// R4: persistent kernel (single dispatch, 1000 blocks = all co-resident at
// 4 blocks/CU) with a FIXED grid barrier:
//   - R3's bug: ACQUIRE poll -> buffer_inv (L1+L2 invalidate) on EVERY spin
//     iteration = cache-destruction storm -> 139 GB/s, 8.3 ms.
//   - R4: relaxed polls (coherence-point load, no invalidate), one
//     release fence before arrival (wbL2), one acquire fence after exit
//     (single inv per wave per step). rocPRIM/coop-groups pattern.
// Per-thread work: 4 consecutive z-levels of one float4 x-group (z-blocking:
// center loads shared). therapy + scalars live in registers for all 30 steps.

#define NX 160
#define NY 160
#define NZ 160
#define NXQ 40                    // float4 groups per row
#define NPLANE (NX * NY)          // 25600 floats per z-plane
#define NZQ 40                    // z-quads per column
#define NWORK (NXQ * NY * NZQ)    // 256000 threads = 1000 blocks x 256
#define NBLOCKS (NWORK / 256)     // 1000 <= 1024 co-residency capacity
#define NSTEPS 30

__device__ __forceinline__ float4 ld4(const float* p) {
    return *reinterpret_cast<const float4*>(p);
}

__device__ __forceinline__ void grid_barrier(unsigned int* cnt, unsigned int target) {
    // All block stores complete before s_barrier (compiler emits vmcnt(0)).
    __syncthreads();
    if (threadIdx.x == 0) {
        // Publish this block's stores to the coherence point, then arrive.
        __builtin_amdgcn_fence(__ATOMIC_RELEASE, "agent");
        __hip_atomic_fetch_add(cnt, 1u, __ATOMIC_RELAXED, __HIP_MEMORY_SCOPE_AGENT);
        // RELAXED polls: no cache invalidate per iteration (R3's fatal flaw).
        while (__hip_atomic_load(cnt, __ATOMIC_RELAXED, __HIP_MEMORY_SCOPE_AGENT) < target) {
            __builtin_amdgcn_s_sleep(2);
        }
    }
    __syncthreads();
    // Single invalidate AFTER the barrier so subsequent loads see peers' data.
    __builtin_amdgcn_fence(__ATOMIC_ACQUIRE, "agent");
}

__global__ void init_counter(unsigned int* cnt) {
    *cnt = 0u;
}

__global__ __launch_bounds__(256, 4) void therapy_persistent(
    const float* __restrict__ c_init,
    const float* __restrict__ ther,
    float* __restrict__ bufA,         // ws ping buffer
    float* __restrict__ out,          // d_out, doubles as pong buffer
    unsigned int* __restrict__ counter,
    const float* __restrict__ Dp,
    const float* __restrict__ rhop,
    const float* __restrict__ dtp,
    const int* __restrict__ stepsp)
{
    const int tid = blockIdx.x * blockDim.x + threadIdx.x;

    const int xq = tid % NXQ;
    const int y  = (tid / NXQ) % NY;
    const int zq = tid / (NXQ * NY);          // 0..39, owns z = 4*zq .. 4*zq+3
    const int idx0 = ((zq * 4) * NY + y) * NX + xq * 4;

    // Always-valid clamped offsets; boundary values masked to zero below.
    const int offym = (y > 0)        ? -NX : 0;
    const int offyp = (y < NY - 1)   ?  NX : 0;
    const int offxl = (xq > 0)       ? -1  : 0;
    const int offxr = (xq < NXQ - 1) ?  4  : 3;
    const int offzm = (zq > 0)       ? -NPLANE     : 0;
    const int offzp = (zq < NZQ - 1) ?  4 * NPLANE : 3 * NPLANE;

    const float D       = *Dp;
    const float rho     = *rhop;
    const float delta_t = *dtp / (float)(*stepsp);
    const float4 zero4  = make_float4(0.f, 0.f, 0.f, 0.f);

    // therapy is time-invariant: hold in registers for all 30 steps
    float4 tm[4];
    #pragma unroll
    for (int i = 0; i < 4; ++i) tm[i] = ld4(ther + idx0 + i * NPLANE);

    const float* src = c_init;
    for (int s = 0; s < NSTEPS; ++s) {
        float* dst = (s & 1) ? out : bufA;    // step 29 (odd) lands in d_out

        const float* sp = src + idx0;
        float4 cz[6];                         // z-1, z, z+1, z+2, z+3, z+4
        float4 ymv[4], ypv[4];
        float  xlv[4], xrv[4];
        #pragma unroll
        for (int i = 0; i < 4; ++i) {
            cz[i + 1] = ld4(sp + i * NPLANE);
            ymv[i]    = ld4(sp + i * NPLANE + offym);
            ypv[i]    = ld4(sp + i * NPLANE + offyp);
            xlv[i]    = sp[i * NPLANE + offxl];
            xrv[i]    = sp[i * NPLANE + offxr];
        }
        cz[0] = ld4(sp + offzm);
        cz[5] = ld4(sp + offzp);

        if (zq == 0)       cz[0] = zero4;
        if (zq == NZQ - 1) cz[5] = zero4;
        if (y == 0)      { ymv[0] = ymv[1] = ymv[2] = ymv[3] = zero4; }
        if (y == NY - 1) { ypv[0] = ypv[1] = ypv[2] = ypv[3] = zero4; }
        if (xq == 0)       { xlv[0] = xlv[1] = xlv[2] = xlv[3] = 0.f; }
        if (xq == NXQ - 1) { xrv[0] = xrv[1] = xrv[2] = xrv[3] = 0.f; }

        #pragma unroll
        for (int i = 0; i < 4; ++i) {
            const float4 cc = cz[i + 1];
            const float4 zm = cz[i];
            const float4 zp = cz[i + 2];
            float4 o;
            float lap, g;
            lap = xlv[i] + cc.y + ymv[i].x + ypv[i].x + zm.x + zp.x - 6.f * cc.x;
            g   = D * lap + rho * cc.x * (1.f - cc.x) - 2.f * tm[i].x * cc.x;
            o.x = fminf(fmaxf(cc.x + g * delta_t, 0.f), 1.f);
            lap = cc.x + cc.z + ymv[i].y + ypv[i].y + zm.y + zp.y - 6.f * cc.y;
            g   = D * lap + rho * cc.y * (1.f - cc.y) - 2.f * tm[i].y * cc.y;
            o.y = fminf(fmaxf(cc.y + g * delta_t, 0.f), 1.f);
            lap = cc.y + cc.w + ymv[i].z + ypv[i].z + zm.z + zp.z - 6.f * cc.z;
            g   = D * lap + rho * cc.z * (1.f - cc.z) - 2.f * tm[i].z * cc.z;
            o.z = fminf(fmaxf(cc.z + g * delta_t, 0.f), 1.f);
            lap = cc.z + xrv[i] + ymv[i].w + ypv[i].w + zm.w + zp.w - 6.f * cc.w;
            g   = D * lap + rho * cc.w * (1.f - cc.w) - 2.f * tm[i].w * cc.w;
            o.w = fminf(fmaxf(cc.w + g * delta_t, 0.f), 1.f);
            *reinterpret_cast<float4*>(dst + idx0 + i * NPLANE) = o;
        }

        if (s != NSTEPS - 1) {
            grid_barrier(counter, (unsigned)(s + 1) * NBLOCKS);
        }
        src = dst;
    }
}

extern "C" void kernel_launch(void* const* d_in, const int* in_sizes, int n_in,
                              void* d_out, int out_size, void* d_ws, size_t ws_size,
                              hipStream_t stream) {
    const float* c_init = (const float*)d_in[0];
    const float* Dp     = (const float*)d_in[1];
    const float* rhop   = (const float*)d_in[2];
    const float* dtp    = (const float*)d_in[3];
    const float* ther   = (const float*)d_in[4];
    const int*   stepsp = (const int*)d_in[5];

    float* out = (float*)d_out;
    unsigned int* counter = (unsigned int*)d_ws;          // 1 cacheline
    float* bufA = (float*)((char*)d_ws + 1024);           // 16.4 MB ping buffer

    // ws is re-poisoned 0xAA before every call: zero the barrier counter first
    // (same stream -> ordered before the persistent kernel).
    init_counter<<<1, 1, 0, stream>>>(counter);

    therapy_persistent<<<dim3(NBLOCKS), dim3(256), 0, stream>>>(
        c_init, ther, bufA, out, counter, Dp, rhop, dtp, stepsp);
}

// Round 5
// 2109.593 us; speedup vs baseline: 3.9522x; 1.9014x over previous
//
#include <hip/hip_runtime.h>

// 3D reaction-diffusion tumor solver, 160^3 f32, 30 explicit Euler steps.
// c_{t+1} = clip(c + (D*lap(c) + rho*c*(1-c) - 2*ther*c)*dt/steps, 0, 1)
//
// R5: persistent kernel + TWO-LEVEL grid barrier.
//   R3 bug: acquire-poll -> buffer_inv storm (8.3 ms).
//   R4 bug: 1000 pollers + 1000 atomics on ONE cacheline at s_sleep(2)
//           -> L3 line saturation, ~127 us/barrier (3.9 ms total).
//   R5: 25 groups x 40 blocks; per-group counter + go-flag on private
//       128B lines; root counter touched only by 25 leaders. Max ~40
//       accessors/line at ~107ns poll interval. Fences as R4 (release
//       before arrival, acquire after exit - the proven-correct pair).
// Work decomposition: thread owns 4 consecutive z-levels of one float4
// x-group (center column loads shared); therapy + scalars in registers
// across all 30 steps.

#define NX 160
#define NY 160
#define NZ 160
#define NXQ 40                    // float4 groups per row
#define NPLANE (NX * NY)          // 25600 floats per z-plane
#define NZQ 40                    // z-quads per column
#define NWORK (NXQ * NY * NZQ)    // 256000 threads = 1000 blocks x 256
#define NBLOCKS (NWORK / 256)     // 1000 (<= co-residency capacity)
#define NSTEPS 30

#define NGROUP 25                 // barrier groups
#define GSIZE  40                 // blocks per group (25*40 = 1000)
#define LINE   32                 // u32s per 128B cacheline stride
// counter area layout (u32 index): root @0, group g @ LINE*(1+g),
// go flag g @ LINE*(1+NGROUP+g). Total 51 lines = 6528 B < 8192.
#define CTR_WORDS (LINE * (1 + 2 * NGROUP))

__device__ __forceinline__ float4 ld4(const float* p) {
    return *reinterpret_cast<const float4*>(p);
}

__device__ __forceinline__ void grid_barrier2(unsigned* ctrs, int g, bool leader,
                                              unsigned epoch) {
    __syncthreads();
    if (threadIdx.x == 0) {
        unsigned* gcnt = ctrs + LINE * (1 + g);
        unsigned* go   = ctrs + LINE * (1 + NGROUP + g);
        unsigned* root = ctrs;
        // Publish this block's stores to the coherence point, then arrive.
        __builtin_amdgcn_fence(__ATOMIC_RELEASE, "agent");
        __hip_atomic_fetch_add(gcnt, 1u, __ATOMIC_RELAXED, __HIP_MEMORY_SCOPE_AGENT);
        if (leader) {
            while (__hip_atomic_load(gcnt, __ATOMIC_RELAXED, __HIP_MEMORY_SCOPE_AGENT)
                   < epoch * GSIZE)
                __builtin_amdgcn_s_sleep(4);
            __hip_atomic_fetch_add(root, 1u, __ATOMIC_RELAXED, __HIP_MEMORY_SCOPE_AGENT);
            while (__hip_atomic_load(root, __ATOMIC_RELAXED, __HIP_MEMORY_SCOPE_AGENT)
                   < epoch * NGROUP)
                __builtin_amdgcn_s_sleep(4);
            __hip_atomic_store(go, epoch, __ATOMIC_RELAXED, __HIP_MEMORY_SCOPE_AGENT);
        } else {
            while (__hip_atomic_load(go, __ATOMIC_RELAXED, __HIP_MEMORY_SCOPE_AGENT)
                   < epoch)
                __builtin_amdgcn_s_sleep(4);
        }
    }
    __syncthreads();
    // Single invalidate AFTER the barrier so subsequent loads see peers' data.
    __builtin_amdgcn_fence(__ATOMIC_ACQUIRE, "agent");
}

__global__ void init_counters(unsigned int* ctrs) {
    for (int i = threadIdx.x; i < CTR_WORDS; i += blockDim.x) ctrs[i] = 0u;
}

__global__ __launch_bounds__(256, 4) void therapy_persistent(
    const float* __restrict__ c_init,
    const float* __restrict__ ther,
    float* __restrict__ bufA,         // ws ping buffer
    float* __restrict__ out,          // d_out, doubles as pong buffer
    unsigned int* __restrict__ ctrs,
    const float* __restrict__ Dp,
    const float* __restrict__ rhop,
    const float* __restrict__ dtp,
    const int* __restrict__ stepsp)
{
    const int tid = blockIdx.x * blockDim.x + threadIdx.x;
    const int grp    = blockIdx.x / GSIZE;
    const bool leader = (blockIdx.x % GSIZE) == 0;

    const int xq = tid % NXQ;
    const int y  = (tid / NXQ) % NY;
    const int zq = tid / (NXQ * NY);          // 0..39, owns z = 4*zq .. 4*zq+3
    const int idx0 = ((zq * 4) * NY + y) * NX + xq * 4;

    // Always-valid clamped offsets; boundary values masked to zero below.
    const int offym = (y > 0)        ? -NX : 0;
    const int offyp = (y < NY - 1)   ?  NX : 0;
    const int offxl = (xq > 0)       ? -1  : 0;
    const int offxr = (xq < NXQ - 1) ?  4  : 3;
    const int offzm = (zq > 0)       ? -NPLANE     : 0;
    const int offzp = (zq < NZQ - 1) ?  4 * NPLANE : 3 * NPLANE;

    const float D       = *Dp;
    const float rho     = *rhop;
    const float delta_t = *dtp / (float)(*stepsp);
    const float4 zero4  = make_float4(0.f, 0.f, 0.f, 0.f);

    // therapy is time-invariant: hold in registers for all 30 steps
    float4 tm[4];
    #pragma unroll
    for (int i = 0; i < 4; ++i) tm[i] = ld4(ther + idx0 + i * NPLANE);

    const float* src = c_init;
    for (int s = 0; s < NSTEPS; ++s) {
        float* dst = (s & 1) ? out : bufA;    // step 29 (odd) lands in d_out

        const float* sp = src + idx0;
        float4 cz[6];                         // z-1, z, z+1, z+2, z+3, z+4
        float4 ymv[4], ypv[4];
        float  xlv[4], xrv[4];
        #pragma unroll
        for (int i = 0; i < 4; ++i) {
            cz[i + 1] = ld4(sp + i * NPLANE);
            ymv[i]    = ld4(sp + i * NPLANE + offym);
            ypv[i]    = ld4(sp + i * NPLANE + offyp);
            xlv[i]    = sp[i * NPLANE + offxl];
            xrv[i]    = sp[i * NPLANE + offxr];
        }
        cz[0] = ld4(sp + offzm);
        cz[5] = ld4(sp + offzp);

        if (zq == 0)       cz[0] = zero4;
        if (zq == NZQ - 1) cz[5] = zero4;
        if (y == 0)      { ymv[0] = ymv[1] = ymv[2] = ymv[3] = zero4; }
        if (y == NY - 1) { ypv[0] = ypv[1] = ypv[2] = ypv[3] = zero4; }
        if (xq == 0)       { xlv[0] = xlv[1] = xlv[2] = xlv[3] = 0.f; }
        if (xq == NXQ - 1) { xrv[0] = xrv[1] = xrv[2] = xrv[3] = 0.f; }

        #pragma unroll
        for (int i = 0; i < 4; ++i) {
            const float4 cc = cz[i + 1];
            const float4 zm = cz[i];
            const float4 zp = cz[i + 2];
            float4 o;
            float lap, g;
            lap = xlv[i] + cc.y + ymv[i].x + ypv[i].x + zm.x + zp.x - 6.f * cc.x;
            g   = D * lap + rho * cc.x * (1.f - cc.x) - 2.f * tm[i].x * cc.x;
            o.x = fminf(fmaxf(cc.x + g * delta_t, 0.f), 1.f);
            lap = cc.x + cc.z + ymv[i].y + ypv[i].y + zm.y + zp.y - 6.f * cc.y;
            g   = D * lap + rho * cc.y * (1.f - cc.y) - 2.f * tm[i].y * cc.y;
            o.y = fminf(fmaxf(cc.y + g * delta_t, 0.f), 1.f);
            lap = cc.y + cc.w + ymv[i].z + ypv[i].z + zm.z + zp.z - 6.f * cc.z;
            g   = D * lap + rho * cc.z * (1.f - cc.z) - 2.f * tm[i].z * cc.z;
            o.z = fminf(fmaxf(cc.z + g * delta_t, 0.f), 1.f);
            lap = cc.z + xrv[i] + ymv[i].w + ypv[i].w + zm.w + zp.w - 6.f * cc.w;
            g   = D * lap + rho * cc.w * (1.f - cc.w) - 2.f * tm[i].w * cc.w;
            o.w = fminf(fmaxf(cc.w + g * delta_t, 0.f), 1.f);
            *reinterpret_cast<float4*>(dst + idx0 + i * NPLANE) = o;
        }

        if (s != NSTEPS - 1) {
            grid_barrier2(ctrs, grp, leader, (unsigned)(s + 1));
        }
        src = dst;
    }
}

extern "C" void kernel_launch(void* const* d_in, const int* in_sizes, int n_in,
                              void* d_out, int out_size, void* d_ws, size_t ws_size,
                              hipStream_t stream) {
    const float* c_init = (const float*)d_in[0];
    const float* Dp     = (const float*)d_in[1];
    const float* rhop   = (const float*)d_in[2];
    const float* dtp    = (const float*)d_in[3];
    const float* ther   = (const float*)d_in[4];
    const int*   stepsp = (const int*)d_in[5];

    float* out = (float*)d_out;
    unsigned int* ctrs = (unsigned int*)d_ws;             // 51 cachelines
    float* bufA = (float*)((char*)d_ws + 8192);           // 16.4 MB ping buffer

    // ws is re-poisoned 0xAA before every call: zero all barrier lines first
    // (same stream -> ordered before the persistent kernel).
    init_counters<<<1, 256, 0, stream>>>(ctrs);

    therapy_persistent<<<dim3(NBLOCKS), dim3(256), 0, stream>>>(
        c_init, ther, bufA, out, ctrs, Dp, rhop, dtp, stepsp);
}

// Round 6
// 720.909 us; speedup vs baseline: 11.5652x; 2.9263x over previous
//
#include <hip/hip_runtime.h>

// 3D reaction-diffusion tumor solver, 160^3 f32, 30 explicit Euler steps.
// step(c) = clip(c + (D*lap(c) + rho*c*(1-c) - 2*ther*c)*dt/steps, 0, 1)
//
// R6: TWO steps fused per launch, 15 launches, NO grid barriers.
//   R3-R5 lesson: in-kernel cross-XCD coherence (wbl2/inv fences) costs
//   ~60 us/step no matter how the barrier counters are arranged; the CP
//   does the same flush at kernel boundaries for ~free (R2: 476 us total).
//   So: kernel boundaries are the only sync. Fusing 2 steps per kernel
//   halves both the launch count and the therapy re-read traffic.
// Per block: phase 1 computes u1 = step(u0) over a halo tile 34x34x10
//   into LDS (row stride 35 -> 2-way LDS banks = free); __syncthreads;
//   phase 2 computes u2 = step(u1) for the 32x32x8 core, writes global.
//   Halo cells outside the domain are 0 (matches conv "SAME" zero-pad).
// Grid: 5x5x20 = 500 blocks x 256 threads; LDS 47.6 KB -> 3 blocks/CU.

#define NXg 160
#define TX 32
#define TY 32
#define TZ 8
#define HX 34           // TX+2 (logical)
#define HY 34
#define HZ 10           // TZ+2
#define HXP 35          // padded LDS row stride (+1 breaks 4-way bank conflict)
#define GBX 5
#define GBY 5
#define GBZ 20
#define NBLK (GBX * GBY * GBZ)   // 500
#define NLAUNCH 15               // 15 x 2 fused steps = 30

__global__ __launch_bounds__(256) void therapy_fused2(
    const float* __restrict__ src,
    const float* __restrict__ ther,
    float* __restrict__ dst,
    const float* __restrict__ Dp,
    const float* __restrict__ rhop,
    const float* __restrict__ dtp,
    const int* __restrict__ stepsp)
{
    __shared__ float u1[HZ][HY][HXP];     // 10*34*35*4 = 47600 B

    const int b  = blockIdx.x;
    const int bx = b % GBX;
    const int by = (b / GBX) % GBY;
    const int bz = b / (GBX * GBY);
    const int x0 = bx * TX, y0 = by * TY, z0 = bz * TZ;

    const float D       = *Dp;
    const float rho     = *rhop;
    const float delta_t = *dtp / (float)(*stepsp);

    const int t = threadIdx.x;

    // ---------------- phase 1: u1 = step(u0) over halo tile ----------------
    // 10 planes of 34x34 = 1156 cells; 256 threads stride the plane.
    const int ly_init = t / HX;           // one const-div per thread
    const int lx_init = t % HX;
    for (int lz = 0; lz < HZ; ++lz) {
        const int gz = z0 + lz - 1;
        int lly = ly_init, llx = lx_init;
        for (int j = t; j < HY * HX; j += 256) {
            const int gy = y0 + lly - 1;
            const int gx = x0 + llx - 1;
            float v = 0.f;
            if (gx >= 0 && gx < NXg && gy >= 0 && gy < NXg && gz >= 0 && gz < NXg) {
                const int gi = (gz * NXg + gy) * NXg + gx;
                const float cc  = src[gi];
                const float tmv = ther[gi];
                const float xl = (gx > 0)        ? src[gi - 1]     : 0.f;
                const float xr = (gx < NXg - 1)  ? src[gi + 1]     : 0.f;
                const float ym = (gy > 0)        ? src[gi - NXg]   : 0.f;
                const float yp = (gy < NXg - 1)  ? src[gi + NXg]   : 0.f;
                const float zm = (gz > 0)        ? src[gi - NXg*NXg] : 0.f;
                const float zp = (gz < NXg - 1)  ? src[gi + NXg*NXg] : 0.f;
                const float lap = xl + xr + ym + yp + zm + zp - 6.f * cc;
                const float g   = D * lap + rho * cc * (1.f - cc) - 2.f * tmv * cc;
                v = fminf(fmaxf(cc + g * delta_t, 0.f), 1.f);
            }
            u1[lz][lly][llx] = v;
            // advance (lly,llx) by 256 = 7*34 + 18 (no div in the loop)
            lly += 7; llx += 18;
            if (llx >= HX) { llx -= HX; lly += 1; }
        }
    }
    __syncthreads();

    // ---------------- phase 2: u2 = step(u1) over 32x32x8 core ----------------
    const int xq  = t & 7;                // 8 float4 groups per 32-wide row
    const int yy  = t >> 3;               // 0..31
    const int gx2 = x0 + xq * 4;
    const int gy2 = y0 + yy;
    const int lxx = xq * 4 + 1;           // LDS x of first element
    const int lyy = yy + 1;

    for (int zz = 0; zz < TZ; ++zz) {
        const int gz2 = z0 + zz;
        const int lz  = zz + 1;
        const int gi  = (gz2 * NXg + gy2) * NXg + gx2;
        const float4 tm = *reinterpret_cast<const float4*>(ther + gi);
        const float* tmp = reinterpret_cast<const float*>(&tm);
        float4 o;
        float* op = reinterpret_cast<float*>(&o);
        #pragma unroll
        for (int e = 0; e < 4; ++e) {
            const float cc = u1[lz][lyy][lxx + e];
            const float xl = u1[lz][lyy][lxx + e - 1];
            const float xr = u1[lz][lyy][lxx + e + 1];
            const float ym = u1[lz][lyy - 1][lxx + e];
            const float yp = u1[lz][lyy + 1][lxx + e];
            const float zm = u1[lz - 1][lyy][lxx + e];
            const float zp = u1[lz + 1][lyy][lxx + e];
            const float lap = xl + xr + ym + yp + zm + zp - 6.f * cc;
            const float g   = D * lap + rho * cc * (1.f - cc) - 2.f * tmp[e] * cc;
            op[e] = fminf(fmaxf(cc + g * delta_t, 0.f), 1.f);
        }
        *reinterpret_cast<float4*>(dst + gi) = o;
    }
}

extern "C" void kernel_launch(void* const* d_in, const int* in_sizes, int n_in,
                              void* d_out, int out_size, void* d_ws, size_t ws_size,
                              hipStream_t stream) {
    const float* c_init = (const float*)d_in[0];
    const float* Dp     = (const float*)d_in[1];
    const float* rhop   = (const float*)d_in[2];
    const float* dtp    = (const float*)d_in[3];
    const float* ther   = (const float*)d_in[4];
    const int*   stepsp = (const int*)d_in[5];

    float* bufA = (float*)d_out;   // even launches write here; launch 14 is final
    float* bufB = (float*)d_ws;    // odd launches write here (16.4 MB)

    const dim3 grid(NBLK), block(256);

    // 15 launches x 2 fused steps. dst(k) = A if k even else B;
    // src(0) = c_init, src(k) = dst(k-1). dst(14) = A = d_out.
    const float* src = c_init;
    for (int k = 0; k < NLAUNCH; ++k) {
        float* dst = (k & 1) ? bufB : bufA;
        therapy_fused2<<<grid, block, 0, stream>>>(
            src, ther, dst, Dp, rhop, dtp, stepsp);
        src = dst;
    }
}

// Round 7
// 660.911 us; speedup vs baseline: 12.6151x; 1.0908x over previous
//
#include <hip/hip_runtime.h>

// 3D reaction-diffusion tumor solver, 160^3 f32, 30 explicit Euler steps.
// step(c) = clip(c + (D*lap(c) + rho*c*(1-c) - 2*ther*c)*dt/steps, 0, 1)
//
// R7: 2 steps fused per launch (15 launches, kernel-boundary sync only —
// R3-R5 proved in-kernel cross-XCD fences cost ~60us/step). Fixes R6's
// latency-bound kernel (48us/dispatch, VALUBusy 16%, occupancy 19%):
//  - rolling 3-plane LDS window for u1 (19.6 KB vs 47.6 KB)
//  - TZ=4 -> 1000 blocks (~4/CU, 16 waves/CU)
//  - phase 1: aligned float4 global loads + branchless clamp/mask (R2 pattern)
//  - phase 2: one x per lane -> conflict-free LDS reads, coalesced stores
// Tile: core 32x32x4 per block; u1 halo tile 34x34x6 computed in f4 groups
// covering x in [x0-4, x0+36) (10 groups x 34 rows = 340 f4 cells/plane).

#define NXg 160
#define NPL (NXg * NXg)          // 25600
#define TX 32
#define TY 32
#define TZ 4
#define GBX 5
#define GBY 5
#define GBZ 40
#define NBLK (GBX * GBY * GBZ)   // 1000
#define NLAUNCH 15               // 15 x 2 fused steps = 30
#define LSTR 48                  // LDS row stride (f4-aligned, 2-way banks max)
#define PCELLS 340               // 10 f4-groups x 34 rows per u1 plane

typedef float (*lds_t)[34][LSTR];

__device__ __forceinline__ float4 ld4(const float* p) {
    return *reinterpret_cast<const float4*>(p);
}

__device__ __forceinline__ void compute_u1_plane(
    const float* __restrict__ src, const float* __restrict__ ther,
    lds_t u1s, int slot, int gz, int x0, int y0, int t,
    float D, float rho, float delta_t)
{
    const float4 zero4 = make_float4(0.f, 0.f, 0.f, 0.f);
    for (int c = t; c < PCELLS; c += 256) {
        const int row = c / 10;
        const int g   = c - row * 10;
        const int gy  = y0 - 1 + row;
        const int gx  = x0 - 4 + 4 * g;
        float4 v = zero4;
        const bool in = (gx >= 0) & (gx <= NXg - 4) & (gy >= 0) & (gy <= NXg - 1)
                      & (gz >= 0) & (gz <= NXg - 1);
        if (in) {
            const int gi = (gz * NXg + gy) * NXg + gx;
            const float4 cc = ld4(src + gi);
            const float4 tm = ld4(ther + gi);
            float4 ym = ld4(src + gi + ((gy > 0)       ? -NXg : 0));
            float4 yp = ld4(src + gi + ((gy < NXg - 1) ?  NXg : 0));
            float4 zm = ld4(src + gi + ((gz > 0)       ? -NPL : 0));
            float4 zp = ld4(src + gi + ((gz < NXg - 1) ?  NPL : 0));
            float  xl = src[gi + ((gx > 0)       ? -1 : 0)];
            float  xr = src[gi + ((gx < NXg - 4) ?  4 : 3)];
            if (gy == 0)       ym = zero4;
            if (gy == NXg - 1) yp = zero4;
            if (gz == 0)       zm = zero4;
            if (gz == NXg - 1) zp = zero4;
            if (gx == 0)       xl = 0.f;
            if (gx == NXg - 4) xr = 0.f;
            float lap, gr;
            lap = xl   + cc.y + ym.x + yp.x + zm.x + zp.x - 6.f * cc.x;
            gr  = D * lap + rho * cc.x * (1.f - cc.x) - 2.f * tm.x * cc.x;
            v.x = fminf(fmaxf(cc.x + gr * delta_t, 0.f), 1.f);
            lap = cc.x + cc.z + ym.y + yp.y + zm.y + zp.y - 6.f * cc.y;
            gr  = D * lap + rho * cc.y * (1.f - cc.y) - 2.f * tm.y * cc.y;
            v.y = fminf(fmaxf(cc.y + gr * delta_t, 0.f), 1.f);
            lap = cc.y + cc.w + ym.z + yp.z + zm.z + zp.z - 6.f * cc.z;
            gr  = D * lap + rho * cc.z * (1.f - cc.z) - 2.f * tm.z * cc.z;
            v.z = fminf(fmaxf(cc.z + gr * delta_t, 0.f), 1.f);
            lap = cc.z + xr   + ym.w + yp.w + zm.w + zp.w - 6.f * cc.w;
            gr  = D * lap + rho * cc.w * (1.f - cc.w) - 2.f * tm.w * cc.w;
            v.w = fminf(fmaxf(cc.w + gr * delta_t, 0.f), 1.f);
        }
        *reinterpret_cast<float4*>(&u1s[slot][row][4 * g]) = v;  // 16B-aligned
    }
}

__global__ __launch_bounds__(256) void therapy_fused2(
    const float* __restrict__ src,
    const float* __restrict__ ther,
    float* __restrict__ dst,
    const float* __restrict__ Dp,
    const float* __restrict__ rhop,
    const float* __restrict__ dtp,
    const int* __restrict__ stepsp)
{
    __shared__ float u1s_raw[3][34][LSTR];    // 19,584 B
    lds_t u1s = u1s_raw;

    const int b  = blockIdx.x;
    const int bx = b % GBX;
    const int by = (b / GBX) % GBY;
    const int bz = b / (GBX * GBY);
    const int x0 = bx * TX, y0 = by * TY, z0 = bz * TZ;

    const float D       = *Dp;
    const float rho     = *rhop;
    const float delta_t = *dtp / (float)(*stepsp);

    const int t = threadIdx.x;

    // preload u1 planes gz = z0-1 (slot 0), z0 (slot 1)
    compute_u1_plane(src, ther, u1s, 0, z0 - 1, x0, y0, t, D, rho, delta_t);
    compute_u1_plane(src, ther, u1s, 1, z0,     x0, y0, t, D, rho, delta_t);

    const int x  = t & 31;       // lane x -> conflict-free LDS banks
    const int yb = t >> 5;       // 0..7
    const int lx = x + 4;

    #pragma unroll
    for (int zz = 0; zz < TZ; ++zz) {
        compute_u1_plane(src, ther, u1s, (zz + 2) % 3, z0 + zz + 1,
                         x0, y0, t, D, rho, delta_t);
        __syncthreads();
        const int s0 = zz % 3, s1 = (zz + 1) % 3, s2 = (zz + 2) % 3;
        #pragma unroll
        for (int ys = 0; ys < 4; ++ys) {
            const int y  = ys * 8 + yb;
            const int gi = ((z0 + zz) * NXg + (y0 + y)) * NXg + x0 + x;
            const float tmv = ther[gi];
            const float cc = u1s[s1][y + 1][lx];
            const float xl = u1s[s1][y + 1][lx - 1];
            const float xr = u1s[s1][y + 1][lx + 1];
            const float ym = u1s[s1][y    ][lx];
            const float yp = u1s[s1][y + 2][lx];
            const float zm = u1s[s0][y + 1][lx];
            const float zp = u1s[s2][y + 1][lx];
            const float lap = xl + xr + ym + yp + zm + zp - 6.f * cc;
            const float gr  = D * lap + rho * cc * (1.f - cc) - 2.f * tmv * cc;
            dst[gi] = fminf(fmaxf(cc + gr * delta_t, 0.f), 1.f);
        }
        __syncthreads();   // before overwriting slot zz%3 next iteration
    }
}

extern "C" void kernel_launch(void* const* d_in, const int* in_sizes, int n_in,
                              void* d_out, int out_size, void* d_ws, size_t ws_size,
                              hipStream_t stream) {
    const float* c_init = (const float*)d_in[0];
    const float* Dp     = (const float*)d_in[1];
    const float* rhop   = (const float*)d_in[2];
    const float* dtp    = (const float*)d_in[3];
    const float* ther   = (const float*)d_in[4];
    const int*   stepsp = (const int*)d_in[5];

    float* bufA = (float*)d_out;   // even launches write here; launch 14 final
    float* bufB = (float*)d_ws;    // odd launches write here (16.4 MB)

    const dim3 grid(NBLK), block(256);

    const float* src = c_init;
    for (int k = 0; k < NLAUNCH; ++k) {
        float* dst = (k & 1) ? bufB : bufA;
        therapy_fused2<<<grid, block, 0, stream>>>(
            src, ther, dst, Dp, rhop, dtp, stepsp);
        src = dst;
    }
}